// Round 5
// baseline (436.899 us; speedup 1.0000x reference)
//
#include <hip/hip_runtime.h>
#include <hip/hip_bf16.h>

#define N_TOK 32768
#define INC   256     // input channels
#define HDIM  256     // H*D
#define NH    4
#define DH    64
#define NP    64      // partitions
#define SP    512     // partition size
#define NM    4       // pool seeds
#define NREPS 256     // P*M
#define INV_SCALE 0.125f

typedef __attribute__((ext_vector_type(8))) __bf16 bf16x8;
typedef __attribute__((ext_vector_type(4))) float  f32x4;

static __device__ __forceinline__ ushort f2bf(float f) {
    __hip_bfloat16 h = __float2bfloat16(f);
    return *reinterpret_cast<ushort*>(&h);
}
static __device__ __forceinline__ float bf2f(ushort u) {
    return __uint_as_float(((uint)u) << 16);
}

#define GL_LDS16(g, l) __builtin_amdgcn_global_load_lds( \
    (const __attribute__((address_space(1))) unsigned int*)(g), \
    (__attribute__((address_space(3))) unsigned int*)(l), 16, 0, 0)

// ---------------------------------------------------------------------------
// Kernel 0: fp32 -> bf16 conversion of x and the 3 weight matrices, plus
// WvAvg[d][k] = 0.25 * sum_h Wv[h*64+d][k] (fp32, for the exact x_self path).
// grid 4256 x 256.
// ---------------------------------------------------------------------------
__global__ __launch_bounds__(256) void conv_bf16(
    const float* __restrict__ x,
    const float* __restrict__ Wq, const float* __restrict__ Wk,
    const float* __restrict__ Wv,
    ushort* __restrict__ xb, ushort* __restrict__ Wb,
    float* __restrict__ WvAvg)
{
    const int b = blockIdx.x, tid = threadIdx.x;
    if (b < 4096) {                       // x: 8.4M elements, 8 per thread
        size_t base = (size_t)b * 2048 + tid * 8;
        float4 a = *(const float4*)&x[base];
        float4 c = *(const float4*)&x[base + 4];
        ushort u[8] = {f2bf(a.x), f2bf(a.y), f2bf(a.z), f2bf(a.w),
                       f2bf(c.x), f2bf(c.y), f2bf(c.z), f2bf(c.w)};
        *(int4*)&xb[base] = *(int4*)u;
    } else if (b < 4192) {                // weights: 3 x 65536
        int wb = b - 4096;                // 0..95
        const float* W = (wb < 32) ? Wq : (wb < 64) ? Wk : Wv;
        int mat = wb >> 5;
        size_t off = (size_t)(wb & 31) * 2048 + tid * 8;
        float4 a = *(const float4*)&W[off];
        float4 c = *(const float4*)&W[off + 4];
        ushort u[8] = {f2bf(a.x), f2bf(a.y), f2bf(a.z), f2bf(a.w),
                       f2bf(c.x), f2bf(c.y), f2bf(c.z), f2bf(c.w)};
        *(int4*)&Wb[(size_t)mat * 65536 + off] = *(int4*)u;
    } else {                              // WvAvg: 64 x 256 fp32
        int i = (b - 4192) * 256 + tid;
        int d = i >> 8, k = i & 255;
        WvAvg[i] = 0.25f * (Wv[(size_t)d * 256 + k] +
                            Wv[(size_t)(d + 64) * 256 + k] +
                            Wv[(size_t)(d + 128) * 256 + k] +
                            Wv[(size_t)(d + 192) * 256 + k]);
    }
}

// ---------------------------------------------------------------------------
// Kernel A: QKV projection, bf16 MFMA.  C[128x128] per block, 4 waves each
// 32x128.  BK=64, global_load_lds w=16 with pre-swizzled global source.
// Q is pre-scaled by 1/sqrt(D)=0.125 (exact in bf16) so the attention
// kernels skip the score scaling.  Epilogue via LDS transpose -> b128 stores.
// grid (256 row-tiles, 6 = 3 matrices x 2 col-halves), block 256.
// ---------------------------------------------------------------------------
__global__ __launch_bounds__(256, 2) void qkv_mfma(
    const ushort* __restrict__ xb, const ushort* __restrict__ Wb,
    const float* __restrict__ bq, const float* __restrict__ bk,
    const float* __restrict__ bv,
    ushort* __restrict__ Qb, ushort* __restrict__ Kb, ushort* __restrict__ Vb)
{
    const int bx = blockIdx.x;
    const int by = blockIdx.y;
    const int mat = by >> 1, nh = by & 1;
    const ushort* W = Wb + (size_t)mat * 65536 + (size_t)nh * 128 * 256;
    const float* bias = ((mat == 0) ? bq : (mat == 1) ? bk : bv) + nh * 128;
    ushort* outp = (mat == 0) ? Qb : (mat == 1) ? Kb : Vb;
    const float qscale = (mat == 0) ? INV_SCALE : 1.0f;
    const int rowBase = bx * 128;
    const int colBase = nh * 128;

    __shared__ ushort As[128 * 64];
    __shared__ ushort Bs[128 * 64];
    __shared__ ushort Cs[4][32][136];   // epilogue transpose buffer

    const int tid = threadIdx.x, wave = tid >> 6, lane = tid & 63;
    const int ln = lane & 15, lg = lane >> 4;

    f32x4 acc[2][8];
    #pragma unroll
    for (int mt = 0; mt < 2; ++mt)
        #pragma unroll
        for (int nt = 0; nt < 8; ++nt) acc[mt][nt] = (f32x4){0.f, 0.f, 0.f, 0.f};

    for (int k0 = 0; k0 < 256; k0 += 64) {
        __syncthreads();
        #pragma unroll
        for (int i = 0; i < 4; ++i) {
            int r0 = wave * 32 + i * 8;
            int r  = r0 + (lane >> 3);
            int cc = (lane & 7) ^ (r & 7);       // inverse-swizzled source chunk
            GL_LDS16(&xb[(size_t)(rowBase + r) * 256 + k0 + cc * 8], &As[r0 * 64]);
            GL_LDS16(&W[(size_t)r * 256 + k0 + cc * 8], &Bs[r0 * 64]);
        }
        __syncthreads();

        bf16x8 af[2][2], bfr[8][2];
        #pragma unroll
        for (int mt = 0; mt < 2; ++mt)
            #pragma unroll
            for (int kk = 0; kk < 2; ++kk) {
                int row = wave * 32 + mt * 16 + ln;
                int ch  = (kk * 4 + lg) ^ (row & 7);
                af[mt][kk] = *(const bf16x8*)&As[row * 64 + ch * 8];
            }
        #pragma unroll
        for (int nt = 0; nt < 8; ++nt)
            #pragma unroll
            for (int kk = 0; kk < 2; ++kk) {
                int n  = nt * 16 + ln;
                int ch = (kk * 4 + lg) ^ (n & 7);
                bfr[nt][kk] = *(const bf16x8*)&Bs[n * 64 + ch * 8];
            }
        #pragma unroll
        for (int mt = 0; mt < 2; ++mt)
            #pragma unroll
            for (int nt = 0; nt < 8; ++nt)
                #pragma unroll
                for (int kk = 0; kk < 2; ++kk)
                    acc[mt][nt] = __builtin_amdgcn_mfma_f32_16x16x32_bf16(
                        af[mt][kk], bfr[nt][kk], acc[mt][nt], 0, 0, 0);
    }

    // epilogue: bias + (Q-only) scale + bf16, transpose via LDS, b128 stores
    float bvv[8];
    #pragma unroll
    for (int nt = 0; nt < 8; ++nt) bvv[nt] = bias[nt * 16 + ln];
    #pragma unroll
    for (int mt = 0; mt < 2; ++mt)
        #pragma unroll
        for (int nt = 0; nt < 8; ++nt)
            #pragma unroll
            for (int r = 0; r < 4; ++r)
                Cs[wave][mt * 16 + lg * 4 + r][nt * 16 + ln] =
                    f2bf((acc[mt][nt][r] + bvv[nt]) * qscale);
    __syncthreads();
    #pragma unroll
    for (int i = 0; i < 8; ++i) {
        int c = i * 64 + lane;
        int row = c >> 4, ch = c & 15;
        int4 v = *(const int4*)&Cs[wave][row][ch * 8];
        int outRow = rowBase + wave * 32 + row;
        *(int4*)&outp[(size_t)outRow * 256 + colBase + ch * 8] = v;
    }
}

// ---------------------------------------------------------------------------
// Kernel B: exact fp32 x_self path: dout = beta * (x @ WvAvg^T + bvAvg).
// Runs BEFORE the attention kernels (which atomicAdd on top); replaces the
// memset.  grid 512 x 256, 64 rows x 64 cols per block, 4x4 per thread.
// ---------------------------------------------------------------------------
__global__ __launch_bounds__(256) void xself_gemm(
    const float* __restrict__ x, const float* __restrict__ WvAvg,
    const float* __restrict__ bv, const float* __restrict__ beta_logit,
    float* __restrict__ dout)
{
    __shared__ float xs[64][68];
    __shared__ float wsh[64][68];
    const int rowBase = blockIdx.x * 64;
    const int tid = threadIdx.x;
    const int r = tid >> 4, c = tid & 15;

    float acc[4][4];
    #pragma unroll
    for (int a = 0; a < 4; ++a)
        #pragma unroll
        for (int b = 0; b < 4; ++b) acc[a][b] = 0.f;

    for (int k0 = 0; k0 < 256; k0 += 64) {
        __syncthreads();
        #pragma unroll
        for (int i = 0; i < 4; ++i) {
            int f = tid + 256 * i;
            int m = f >> 4, k4 = (f & 15) * 4;
            *(float4*)&xs[m][k4] = *(const float4*)&x[(size_t)(rowBase + m) * 256 + k0 + k4];
        }
        #pragma unroll
        for (int i = 0; i < 4; ++i) {
            int f = tid + 256 * i;
            int n = f >> 4, k4 = (f & 15) * 4;
            *(float4*)&wsh[n][k4] = *(const float4*)&WvAvg[(size_t)n * 256 + k0 + k4];
        }
        __syncthreads();
        #pragma unroll
        for (int kk = 0; kk < 64; kk += 2) {
            float2 a2[4], b2[4];
            #pragma unroll
            for (int a = 0; a < 4; ++a) a2[a] = *(const float2*)&xs[r + 16 * a][kk];
            #pragma unroll
            for (int b = 0; b < 4; ++b) b2[b] = *(const float2*)&wsh[c + 16 * b][kk];
            #pragma unroll
            for (int a = 0; a < 4; ++a)
                #pragma unroll
                for (int b = 0; b < 4; ++b)
                    acc[a][b] += a2[a].x * b2[b].x + a2[a].y * b2[b].y;
        }
    }

    const float beta = 2.f / (1.f + __expf(-beta_logit[0]));
    #pragma unroll
    for (int b = 0; b < 4; ++b) {
        int col = c + 16 * b;
        float bavg = 0.25f * (bv[col] + bv[col + 64] + bv[col + 128] + bv[col + 192]);
        #pragma unroll
        for (int a = 0; a < 4; ++a)
            dout[(size_t)(rowBase + r + 16 * a) * 64 + col] = beta * (acc[a][b] + bavg);
    }
}

// ---------------------------------------------------------------------------
// Kernel C: seed pooling -> bf16 reps.  grid (64,4), block 512.
// ---------------------------------------------------------------------------
__global__ __launch_bounds__(512) void pool_reps(
    const ushort* __restrict__ Kb, const ushort* __restrict__ Vb,
    const int* __restrict__ idx, const float* __restrict__ seeds,
    ushort* __restrict__ reps_k, ushort* __restrict__ reps_v)
{
    const int p = blockIdx.x, h = blockIdx.y;
    const int tid = threadIdx.x;
    __shared__ float pexp[NM][SP];
    __shared__ float sums[NM];
    __shared__ float sred[NM][8];
    __shared__ float sd[NM][DH];
    __shared__ int   sidx[SP];

    if (tid < NM * DH) {
        int m = tid >> 6, d = tid & 63;
        sd[m][d] = seeds[(size_t)(m * NH + h) * DH + d];
    }
    sidx[tid] = idx[p * SP + tid];
    __syncthreads();

    const int n_s = sidx[tid];
    float kr[64];
    #pragma unroll
    for (int c = 0; c < 8; ++c) {
        int4 raw = *(const int4*)&Kb[(size_t)n_s * HDIM + h * DH + c * 8];
        const ushort* u = (const ushort*)&raw;
        #pragma unroll
        for (int j = 0; j < 8; ++j) kr[c * 8 + j] = bf2f(u[j]);
    }

    float e[NM];
    #pragma unroll
    for (int m = 0; m < NM; ++m) {
        float s = 0.f;
        #pragma unroll
        for (int d = 0; d < 64; ++d) s += kr[d] * sd[m][d];
        e[m] = __expf(s * INV_SCALE);
        pexp[m][tid] = e[m];
    }
    const int lane = tid & 63, w = tid >> 6;
    #pragma unroll
    for (int m = 0; m < NM; ++m) {
        float v = e[m];
        #pragma unroll
        for (int off = 32; off >= 1; off >>= 1) v += __shfl_xor(v, off);
        if (lane == 0) sred[m][w] = v;
    }
    __syncthreads();
    if (tid < NM) {
        float s = 0.f;
        #pragma unroll
        for (int i = 0; i < 8; ++i) s += sred[tid][i];
        sums[tid] = s;
    }
    __syncthreads();

    const int m = w >> 1, kv = w & 1, d = lane;
    const ushort* src = kv ? Vb : Kb;
    float acc = 0.f;
    #pragma unroll 4
    for (int s = 0; s < SP; ++s)
        acc += pexp[m][s] * bf2f(src[(size_t)sidx[s] * HDIM + h * DH + d]);
    ushort* dst = kv ? reps_v : reps_k;
    dst[(size_t)(p * NM + m) * HDIM + h * DH + d] = f2bf(acc / sums[m]);
}

// ---------------------------------------------------------------------------
// Unified MFMA attention (local GATHER=1 over 512 partition keys, global
// GATHER=0 over 256 reps).  Block = 4 waves x 32 queries = 128 queries.
// K-tile = 64 keys -> LDS 32 KB -> 4 blocks/CU.  K staged via
// global_load_lds (pre-swizzled source, linear dest); V transposed via VALU.
// Q arrives pre-scaled by 1/sqrt(D).
// ---------------------------------------------------------------------------
template<int GATHER>
__global__ __launch_bounds__(256, 4) void attn_mfma(
    const ushort* __restrict__ Qb, const ushort* __restrict__ Kb,
    const ushort* __restrict__ Vb,
    const int* __restrict__ idx, const float* __restrict__ bscore,
    const float* __restrict__ alpha_logit, const float* __restrict__ bweight,
    float* __restrict__ dout, int nkeys)
{
    const int h = blockIdx.y;
    const int tid  = threadIdx.x;
    const int wave = tid >> 6;
    const int lane = tid & 63;
    const int ln = lane & 15;
    const int lg = lane >> 4;

    int p = 0, qc = 0;
    if (GATHER) { p = blockIdx.x >> 2; qc = blockIdx.x & 3; }

    __shared__ ushort Ks[64 * 64];       // [key][dim] swizzled, 8 KB
    __shared__ ushort Vt[64 * 64];       // [dim][key] swizzled, 8 KB
    __shared__ ushort Pb[4][32 * 64];    // per-wave [q][key] swizzled, 16 KB

    bf16x8 qf[2][2];
    int tok[2];
    #pragma unroll
    for (int qt = 0; qt < 2; ++qt) {
        int qj = wave * 32 + qt * 16 + ln;
        int t  = GATHER ? idx[p * SP + qc * 128 + qj] : blockIdx.x * 128 + qj;
        tok[qt] = t;
        #pragma unroll
        for (int kc = 0; kc < 2; ++kc)
            qf[qt][kc] = *(const bf16x8*)&Qb[(size_t)t * HDIM + h * DH + kc * 32 + lg * 8];
    }

    f32x4 oa[4][2];
    #pragma unroll
    for (int dt = 0; dt < 4; ++dt)
        #pragma unroll
        for (int qt = 0; qt < 2; ++qt) oa[dt][qt] = (f32x4){0.f, 0.f, 0.f, 0.f};
    float ssum[2] = {0.f, 0.f};

    for (int kt0 = 0; kt0 < nkeys; kt0 += 64) {
        __syncthreads();
        // --- stage K tile via global_load_lds: [key][dim], swizzled source ---
        #pragma unroll
        for (int i = 0; i < 2; ++i) {
            int r0  = wave * 16 + i * 8;          // wave-uniform LDS base row
            int key = r0 + (lane >> 3);
            int dc  = lane & 7;
            int cc  = dc ^ (key & 7);             // inverse-swizzled source chunk
            int row = GATHER ? idx[p * SP + kt0 + key] : (kt0 + key);
            GL_LDS16(&Kb[(size_t)row * HDIM + h * DH + cc * 8], &Ks[r0 * 64]);
        }
        // --- stage V^T tile: [dim][key], packed key-pairs, swizzled ---
        {
            int kp = tid & 31, dc = tid >> 5;     // key-pair 0..31, dim-chunk 0..7
            int r0 = GATHER ? idx[p * SP + kt0 + 2 * kp]     : (kt0 + 2 * kp);
            int r1 = GATHER ? idx[p * SP + kt0 + 2 * kp + 1] : (kt0 + 2 * kp + 1);
            int4 v0 = *(const int4*)&Vb[(size_t)r0 * HDIM + h * DH + dc * 8];
            int4 v1 = *(const int4*)&Vb[(size_t)r1 * HDIM + h * DH + dc * 8];
            const ushort* u0 = (const ushort*)&v0;
            const ushort* u1 = (const ushort*)&v1;
            #pragma unroll
            for (int j = 0; j < 8; ++j) {
                int d = dc * 8 + j;
                uint pk = (uint)u0[j] | ((uint)u1[j] << 16);
                *(uint*)&Vt[d * 64 + (((kp >> 2) ^ (d & 7)) << 3) + (kp & 3) * 2] = pk;
            }
        }
        __syncthreads();

        // --- scores: S^T = K x Q^T, exp, pack to P ---
        #pragma unroll
        for (int ktile = 0; ktile < 4; ++ktile) {
            int kr = ktile * 16 + ln;
            bf16x8 ka0 = *(const bf16x8*)&Ks[kr * 64 + ((lg       ^ (kr & 7)) << 3)];
            bf16x8 ka1 = *(const bf16x8*)&Ks[kr * 64 + (((4 + lg) ^ (kr & 7)) << 3)];
            #pragma unroll
            for (int qt = 0; qt < 2; ++qt) {
                f32x4 s = (f32x4){0.f, 0.f, 0.f, 0.f};
                s = __builtin_amdgcn_mfma_f32_16x16x32_bf16(ka0, qf[qt][0], s, 0, 0, 0);
                s = __builtin_amdgcn_mfma_f32_16x16x32_bf16(ka1, qf[qt][1], s, 0, 0, 0);
                float p0 = __expf(s[0]);
                float p1 = __expf(s[1]);
                float p2 = __expf(s[2]);
                float p3 = __expf(s[3]);
                ssum[qt] += (p0 + p1) + (p2 + p3);
                uint lo = (uint)f2bf(p0) | ((uint)f2bf(p1) << 16);
                uint hi = (uint)f2bf(p2) | ((uint)f2bf(p3) << 16);
                int q  = qt * 16 + ln;
                int k0 = ktile * 16 + lg * 4;
                uint2 pk; pk.x = lo; pk.y = hi;
                *(uint2*)&Pb[wave][q * 64 + (((k0 >> 3) ^ (q & 7)) << 3) + (k0 & 7)] = pk;
            }
        }

        // --- PV: out^T += V^T x P^T ---
        bf16x8 pf[2][2];
        #pragma unroll
        for (int qt = 0; qt < 2; ++qt) {
            int q = qt * 16 + ln;
            #pragma unroll
            for (int kc = 0; kc < 2; ++kc) {
                int k0 = kc * 32 + lg * 8;
                pf[qt][kc] = *(const bf16x8*)&Pb[wave][q * 64 + (((k0 >> 3) ^ (q & 7)) << 3)];
            }
        }
        #pragma unroll
        for (int dt = 0; dt < 4; ++dt) {
            int d = dt * 16 + ln;
            bf16x8 vf[2];
            #pragma unroll
            for (int kc = 0; kc < 2; ++kc) {
                int k0 = kc * 32 + lg * 8;
                vf[kc] = *(const bf16x8*)&Vt[d * 64 + (((k0 >> 3) ^ (d & 7)) << 3)];
            }
            #pragma unroll
            for (int qt = 0; qt < 2; ++qt)
                #pragma unroll
                for (int kc = 0; kc < 2; ++kc)
                    oa[dt][qt] = __builtin_amdgcn_mfma_f32_16x16x32_bf16(
                        vf[kc], pf[qt][kc], oa[dt][qt], 0, 0, 0);
        }
    }

    const float al = alpha_logit[0], bw = bweight[0];
    #pragma unroll
    for (int qt = 0; qt < 2; ++qt) {
        float s = ssum[qt];
        s += __shfl_xor(s, 16);
        s += __shfl_xor(s, 32);
        float a = 1.f / (1.f + __expf(-(al + bw * bscore[tok[qt]])));
        float wgt = (GATHER ? a : (1.f - a)) * 0.25f / s;
        #pragma unroll
        for (int dt = 0; dt < 4; ++dt) {
            #pragma unroll
            for (int r = 0; r < 4; ++r)
                atomicAdd(&dout[(size_t)tok[qt] * DH + dt * 16 + lg * 4 + r],
                          oa[dt][qt][r] * wgt);
        }
    }
}

// ---------------------------------------------------------------------------
extern "C" void kernel_launch(void* const* d_in, const int* in_sizes, int n_in,
                              void* d_out, int out_size, void* d_ws, size_t ws_size,
                              hipStream_t stream)
{
    (void)in_sizes; (void)n_in; (void)ws_size; (void)out_size;
    const float* x      = (const float*)d_in[0];
    const int*   idx    = (const int*)d_in[1];
    const float* bscore = (const float*)d_in[2];
    const float* Wq = (const float*)d_in[3]; const float* bq = (const float*)d_in[4];
    const float* Wk = (const float*)d_in[5]; const float* bk = (const float*)d_in[6];
    const float* Wv = (const float*)d_in[7]; const float* bv = (const float*)d_in[8];
    const float* seeds = (const float*)d_in[9];
    const float* al = (const float*)d_in[10];
    const float* bw = (const float*)d_in[11];
    const float* bl = (const float*)d_in[12];
    float* out = (float*)d_out;

    const size_t NE = (size_t)N_TOK * HDIM;    // 8,388,608
    ushort* xb    = (ushort*)d_ws;
    ushort* Wb    = xb + NE;
    ushort* Qb    = Wb + 3 * 65536;
    ushort* Kb    = Qb + NE;
    ushort* Vb    = Kb + NE;
    ushort* repkb = Vb + NE;
    ushort* repvb = repkb + (size_t)NREPS * HDIM;
    float*  WvAvg = (float*)(repvb + (size_t)NREPS * HDIM);

    conv_bf16 <<<4256, 256, 0, stream>>>(x, Wq, Wk, Wv, xb, Wb, WvAvg);
    qkv_mfma  <<<dim3(256, 6), 256, 0, stream>>>(xb, Wb, bq, bk, bv, Qb, Kb, Vb);
    xself_gemm<<<512, 256, 0, stream>>>(x, WvAvg, bv, bl, out);
    pool_reps <<<dim3(NP, NH), 512, 0, stream>>>(Kb, Vb, idx, seeds, repkb, repvb);
    attn_mfma<1><<<dim3(256, NH), 256, 0, stream>>>(Qb, Kb, Vb, idx, bscore,
                                                    al, bw, out, SP);
    attn_mfma<0><<<dim3(256, NH), 256, 0, stream>>>(Qb, repkb, repvb, idx, bscore,
                                                    al, bw, out, NREPS);
}

// Round 6
// 242.293 us; speedup vs baseline: 1.8032x; 1.8032x over previous
//
#include <hip/hip_runtime.h>
#include <hip/hip_bf16.h>

#define N_TOK 32768
#define INC   256     // input channels
#define HDIM  256     // H*D
#define NH    4
#define DH    64
#define NP    64      // partitions
#define SP    512     // partition size
#define NM    4       // pool seeds
#define NREPS 256     // P*M
#define INV_SCALE 0.125f

typedef __attribute__((ext_vector_type(8))) __bf16 bf16x8;
typedef __attribute__((ext_vector_type(4))) float  f32x4;

static __device__ __forceinline__ ushort f2bf(float f) {
    __hip_bfloat16 h = __float2bfloat16(f);
    return *reinterpret_cast<ushort*>(&h);
}
static __device__ __forceinline__ float bf2f(ushort u) {
    return __uint_as_float(((uint)u) << 16);
}

#define GL_LDS16(g, l) __builtin_amdgcn_global_load_lds( \
    (const __attribute__((address_space(1))) unsigned int*)(g), \
    (__attribute__((address_space(3))) unsigned int*)(l), 16, 0, 0)

// ---------------------------------------------------------------------------
// Kernel A: QKV projection, bf16 MFMA, reading fp32 x / W directly
// (reg-staged convert + swizzled ds_write_b128; no bf16 pre-copy needed).
// C[128x128] per block, 4 waves each 32x128, BK=64.
// Q pre-scaled by 1/sqrt(D)=0.125 (exact in bf16).
// grid (256 row-tiles, 6 = 3 matrices x 2 col-halves), block 256.
// ---------------------------------------------------------------------------
__global__ __launch_bounds__(256, 2) void qkv_mfma(
    const float* __restrict__ x,
    const float* __restrict__ Wq, const float* __restrict__ Wk,
    const float* __restrict__ Wv,
    const float* __restrict__ bq, const float* __restrict__ bk,
    const float* __restrict__ bv,
    ushort* __restrict__ Qb, ushort* __restrict__ Kb, ushort* __restrict__ Vb)
{
    const int bx = blockIdx.x;
    const int by = blockIdx.y;
    const int mat = by >> 1, nh = by & 1;
    const float* Wsel = (mat == 0) ? Wq : (mat == 1) ? Wk : Wv;
    const float* W = Wsel + (size_t)nh * 128 * 256;
    const float* bias = ((mat == 0) ? bq : (mat == 1) ? bk : bv) + nh * 128;
    ushort* outp = (mat == 0) ? Qb : (mat == 1) ? Kb : Vb;
    const float qscale = (mat == 0) ? INV_SCALE : 1.0f;
    const int rowBase = bx * 128;
    const int colBase = nh * 128;

    __shared__ ushort As[128 * 64];
    __shared__ ushort Bs[128 * 64];
    __shared__ ushort Cs[4][32][136];   // epilogue transpose buffer

    const int tid = threadIdx.x, wave = tid >> 6, lane = tid & 63;
    const int ln = lane & 15, lg = lane >> 4;

    f32x4 acc[2][8];
    #pragma unroll
    for (int mt = 0; mt < 2; ++mt)
        #pragma unroll
        for (int nt = 0; nt < 8; ++nt) acc[mt][nt] = (f32x4){0.f, 0.f, 0.f, 0.f};

    for (int k0 = 0; k0 < 256; k0 += 64) {
        __syncthreads();
        #pragma unroll
        for (int i = 0; i < 4; ++i) {
            int f = tid + 256 * i;          // 0..1023
            int row = f >> 3, dc = f & 7;
            int pos = (dc ^ (row & 7)) << 3;
            // A: x rows (fp32 -> bf16)
            {
                const float* src = &x[(size_t)(rowBase + row) * 256 + k0 + dc * 8];
                float4 a = *(const float4*)&src[0];
                float4 b = *(const float4*)&src[4];
                ushort u[8] = {f2bf(a.x), f2bf(a.y), f2bf(a.z), f2bf(a.w),
                               f2bf(b.x), f2bf(b.y), f2bf(b.z), f2bf(b.w)};
                *(int4*)&As[row * 64 + pos] = *(int4*)u;
            }
            // B: W rows (fp32 -> bf16)
            {
                const float* src = &W[(size_t)row * 256 + k0 + dc * 8];
                float4 a = *(const float4*)&src[0];
                float4 b = *(const float4*)&src[4];
                ushort u[8] = {f2bf(a.x), f2bf(a.y), f2bf(a.z), f2bf(a.w),
                               f2bf(b.x), f2bf(b.y), f2bf(b.z), f2bf(b.w)};
                *(int4*)&Bs[row * 64 + pos] = *(int4*)u;
            }
        }
        __syncthreads();

        bf16x8 af[2][2], bfr[8][2];
        #pragma unroll
        for (int mt = 0; mt < 2; ++mt)
            #pragma unroll
            for (int kk = 0; kk < 2; ++kk) {
                int row = wave * 32 + mt * 16 + ln;
                int ch  = (kk * 4 + lg) ^ (row & 7);
                af[mt][kk] = *(const bf16x8*)&As[row * 64 + ch * 8];
            }
        #pragma unroll
        for (int nt = 0; nt < 8; ++nt)
            #pragma unroll
            for (int kk = 0; kk < 2; ++kk) {
                int n  = nt * 16 + ln;
                int ch = (kk * 4 + lg) ^ (n & 7);
                bfr[nt][kk] = *(const bf16x8*)&Bs[n * 64 + ch * 8];
            }
        #pragma unroll
        for (int mt = 0; mt < 2; ++mt)
            #pragma unroll
            for (int nt = 0; nt < 8; ++nt)
                #pragma unroll
                for (int kk = 0; kk < 2; ++kk)
                    acc[mt][nt] = __builtin_amdgcn_mfma_f32_16x16x32_bf16(
                        af[mt][kk], bfr[nt][kk], acc[mt][nt], 0, 0, 0);
    }

    // epilogue: bias + (Q-only) scale + bf16, transpose via LDS, b128 stores
    float bvv[8];
    #pragma unroll
    for (int nt = 0; nt < 8; ++nt) bvv[nt] = bias[nt * 16 + ln];
    #pragma unroll
    for (int mt = 0; mt < 2; ++mt)
        #pragma unroll
        for (int nt = 0; nt < 8; ++nt)
            #pragma unroll
            for (int r = 0; r < 4; ++r)
                Cs[wave][mt * 16 + lg * 4 + r][nt * 16 + ln] =
                    f2bf((acc[mt][nt][r] + bvv[nt]) * qscale);
    __syncthreads();
    #pragma unroll
    for (int i = 0; i < 8; ++i) {
        int c = i * 64 + lane;
        int row = c >> 4, ch = c & 15;
        int4 v = *(const int4*)&Cs[wave][row][ch * 8];
        int outRow = rowBase + wave * 32 + row;
        *(int4*)&outp[(size_t)outRow * 256 + colBase + ch * 8] = v;
    }
}

// ---------------------------------------------------------------------------
// Kernel B: exact fp32 x_self path: dout = beta * (x @ WvAvg^T + bvAvg),
// with WvAvg = 0.25*sum_h Wv rows computed during staging (Wv is L2-hot).
// Plain stores; attention contributions are += later in combine.
// grid 512 x 256.
// ---------------------------------------------------------------------------
__global__ __launch_bounds__(256) void xself_gemm(
    const float* __restrict__ x, const float* __restrict__ Wv,
    const float* __restrict__ bv, const float* __restrict__ beta_logit,
    float* __restrict__ dout)
{
    __shared__ float xs[64][68];
    __shared__ float wsh[64][68];
    const int rowBase = blockIdx.x * 64;
    const int tid = threadIdx.x;
    const int r = tid >> 4, c = tid & 15;

    float acc[4][4];
    #pragma unroll
    for (int a = 0; a < 4; ++a)
        #pragma unroll
        for (int b = 0; b < 4; ++b) acc[a][b] = 0.f;

    for (int k0 = 0; k0 < 256; k0 += 64) {
        __syncthreads();
        #pragma unroll
        for (int i = 0; i < 4; ++i) {
            int f = tid + 256 * i;
            int m = f >> 4, k4 = (f & 15) * 4;
            *(float4*)&xs[m][k4] = *(const float4*)&x[(size_t)(rowBase + m) * 256 + k0 + k4];
        }
        #pragma unroll
        for (int i = 0; i < 4; ++i) {
            int f = tid + 256 * i;
            int n = f >> 4, k4 = (f & 15) * 4;
            float4 w0 = *(const float4*)&Wv[(size_t)n * 256 + k0 + k4];
            float4 w1 = *(const float4*)&Wv[(size_t)(n + 64) * 256 + k0 + k4];
            float4 w2 = *(const float4*)&Wv[(size_t)(n + 128) * 256 + k0 + k4];
            float4 w3 = *(const float4*)&Wv[(size_t)(n + 192) * 256 + k0 + k4];
            float4 wa;
            wa.x = 0.25f * (w0.x + w1.x + w2.x + w3.x);
            wa.y = 0.25f * (w0.y + w1.y + w2.y + w3.y);
            wa.z = 0.25f * (w0.z + w1.z + w2.z + w3.z);
            wa.w = 0.25f * (w0.w + w1.w + w2.w + w3.w);
            *(float4*)&wsh[n][k4] = wa;
        }
        __syncthreads();
        #pragma unroll
        for (int kk = 0; kk < 64; kk += 2) {
            float2 a2[4], b2[4];
            #pragma unroll
            for (int a = 0; a < 4; ++a) a2[a] = *(const float2*)&xs[r + 16 * a][kk];
            #pragma unroll
            for (int b = 0; b < 4; ++b) b2[b] = *(const float2*)&wsh[c + 16 * b][kk];
            #pragma unroll
            for (int a = 0; a < 4; ++a)
                #pragma unroll
                for (int b = 0; b < 4; ++b)
                    acc[a][b] += a2[a].x * b2[b].x + a2[a].y * b2[b].y;
        }
    }

    const float beta = 2.f / (1.f + __expf(-beta_logit[0]));
    #pragma unroll
    for (int b = 0; b < 4; ++b) {
        int col = c + 16 * b;
        float bavg = 0.25f * (bv[col] + bv[col + 64] + bv[col + 128] + bv[col + 192]);
        #pragma unroll
        for (int a = 0; a < 4; ++a)
            dout[(size_t)(rowBase + r + 16 * a) * 64 + col] = beta * (acc[a][b] + bavg);
    }
}

// ---------------------------------------------------------------------------
// Kernel C: seed pooling -> bf16 reps.  grid (64,4), block 512.
// p remapped so partition p lives on XCD p/8 (matches attn_fused).
// ---------------------------------------------------------------------------
__global__ __launch_bounds__(512) void pool_reps(
    const ushort* __restrict__ Kb, const ushort* __restrict__ Vb,
    const int* __restrict__ idx, const float* __restrict__ seeds,
    ushort* __restrict__ reps_k, ushort* __restrict__ reps_v)
{
    const int p = ((blockIdx.x & 7) << 3) | (blockIdx.x >> 3);
    const int h = blockIdx.y;
    const int tid = threadIdx.x;
    __shared__ float pexp[NM][SP];
    __shared__ float sums[NM];
    __shared__ float sred[NM][8];
    __shared__ float sd[NM][DH];
    __shared__ int   sidx[SP];

    if (tid < NM * DH) {
        int m = tid >> 6, d = tid & 63;
        sd[m][d] = seeds[(size_t)(m * NH + h) * DH + d];
    }
    sidx[tid] = idx[p * SP + tid];
    __syncthreads();

    const int n_s = sidx[tid];
    float kr[64];
    #pragma unroll
    for (int c = 0; c < 8; ++c) {
        int4 raw = *(const int4*)&Kb[(size_t)n_s * HDIM + h * DH + c * 8];
        const ushort* u = (const ushort*)&raw;
        #pragma unroll
        for (int j = 0; j < 8; ++j) kr[c * 8 + j] = bf2f(u[j]);
    }

    float e[NM];
    #pragma unroll
    for (int m = 0; m < NM; ++m) {
        float s = 0.f;
        #pragma unroll
        for (int d = 0; d < 64; ++d) s += kr[d] * sd[m][d];
        e[m] = __expf(s * INV_SCALE);
        pexp[m][tid] = e[m];
    }
    const int lane = tid & 63, w = tid >> 6;
    #pragma unroll
    for (int m = 0; m < NM; ++m) {
        float v = e[m];
        #pragma unroll
        for (int off = 32; off >= 1; off >>= 1) v += __shfl_xor(v, off);
        if (lane == 0) sred[m][w] = v;
    }
    __syncthreads();
    if (tid < NM) {
        float s = 0.f;
        #pragma unroll
        for (int i = 0; i < 8; ++i) s += sred[tid][i];
        sums[tid] = s;
    }
    __syncthreads();

    const int m = w >> 1, kv = w & 1, d = lane;
    const ushort* src = kv ? Vb : Kb;
    float acc = 0.f;
    #pragma unroll 8
    for (int s = 0; s < SP; ++s)
        acc += pexp[m][s] * bf2f(src[(size_t)sidx[s] * HDIM + h * DH + d]);
    ushort* dst = kv ? reps_v : reps_k;
    dst[(size_t)(p * NM + m) * HDIM + h * DH + d] = f2bf(acc / sums[m]);
}

// ---------------------------------------------------------------------------
// One attention pass (flash-style, no-max softmax).  GATHER=1: keys via idx;
// GATHER=0: keys are consecutive rows (reps).  Accumulates oa (out^T) and
// per-query exp-sums.  Swapped QK^T: C/D col = query = lane&15.
// ---------------------------------------------------------------------------
template<int GATHER>
static __device__ __forceinline__ void attn_pass(
    const ushort* __restrict__ Kp, const ushort* __restrict__ Vp,
    const int* __restrict__ gidx, int nkeys, int hofs,
    ushort* Ks, ushort* Vt, ushort* Pw,
    const bf16x8 (&qf)[2][2], f32x4 (&oa)[4][2], float (&ssum)[2],
    int tid, int wave, int lane, int ln, int lg)
{
    for (int kt0 = 0; kt0 < nkeys; kt0 += 64) {
        __syncthreads();
        // --- stage K tile via global_load_lds: [key][dim], swizzled source ---
        #pragma unroll
        for (int i = 0; i < 2; ++i) {
            int r0  = wave * 16 + i * 8;          // wave-uniform LDS base row
            int key = r0 + (lane >> 3);
            int dc  = lane & 7;
            int cc  = dc ^ (key & 7);             // inverse-swizzled source chunk
            int row = GATHER ? gidx[kt0 + key] : (kt0 + key);
            GL_LDS16(&Kp[(size_t)row * HDIM + hofs + cc * 8], &Ks[r0 * 64]);
        }
        // --- stage V^T tile: [dim][key], packed key-pairs, swizzled ---
        {
            int kp = tid & 31, dc = tid >> 5;     // key-pair 0..31, dim-chunk 0..7
            int r0 = GATHER ? gidx[kt0 + 2 * kp]     : (kt0 + 2 * kp);
            int r1 = GATHER ? gidx[kt0 + 2 * kp + 1] : (kt0 + 2 * kp + 1);
            int4 v0 = *(const int4*)&Vp[(size_t)r0 * HDIM + hofs + dc * 8];
            int4 v1 = *(const int4*)&Vp[(size_t)r1 * HDIM + hofs + dc * 8];
            const ushort* u0 = (const ushort*)&v0;
            const ushort* u1 = (const ushort*)&v1;
            #pragma unroll
            for (int j = 0; j < 8; ++j) {
                int d = dc * 8 + j;
                uint pk = (uint)u0[j] | ((uint)u1[j] << 16);
                *(uint*)&Vt[d * 64 + (((kp >> 2) ^ (d & 7)) << 3) + (kp & 3) * 2] = pk;
            }
        }
        __syncthreads();

        // --- scores: S^T = K x Q^T, exp, pack to P ---
        #pragma unroll
        for (int ktile = 0; ktile < 4; ++ktile) {
            int kr = ktile * 16 + ln;
            bf16x8 ka0 = *(const bf16x8*)&Ks[kr * 64 + ((lg       ^ (kr & 7)) << 3)];
            bf16x8 ka1 = *(const bf16x8*)&Ks[kr * 64 + (((4 + lg) ^ (kr & 7)) << 3)];
            #pragma unroll
            for (int qt = 0; qt < 2; ++qt) {
                f32x4 s = (f32x4){0.f, 0.f, 0.f, 0.f};
                s = __builtin_amdgcn_mfma_f32_16x16x32_bf16(ka0, qf[qt][0], s, 0, 0, 0);
                s = __builtin_amdgcn_mfma_f32_16x16x32_bf16(ka1, qf[qt][1], s, 0, 0, 0);
                float p0 = __expf(s[0]);
                float p1 = __expf(s[1]);
                float p2 = __expf(s[2]);
                float p3 = __expf(s[3]);
                ssum[qt] += (p0 + p1) + (p2 + p3);
                uint lo = (uint)f2bf(p0) | ((uint)f2bf(p1) << 16);
                uint hi = (uint)f2bf(p2) | ((uint)f2bf(p3) << 16);
                int q  = qt * 16 + ln;
                int k0 = ktile * 16 + lg * 4;
                uint2 pk; pk.x = lo; pk.y = hi;
                *(uint2*)&Pw[q * 64 + (((k0 >> 3) ^ (q & 7)) << 3) + (k0 & 7)] = pk;
            }
        }

        // --- PV: out^T += V^T x P^T ---
        bf16x8 pf[2][2];
        #pragma unroll
        for (int qt = 0; qt < 2; ++qt) {
            int q = qt * 16 + ln;
            #pragma unroll
            for (int kc = 0; kc < 2; ++kc) {
                int k0 = kc * 32 + lg * 8;
                pf[qt][kc] = *(const bf16x8*)&Pw[q * 64 + (((k0 >> 3) ^ (q & 7)) << 3)];
            }
        }
        #pragma unroll
        for (int dt = 0; dt < 4; ++dt) {
            int d = dt * 16 + ln;
            bf16x8 vf[2];
            #pragma unroll
            for (int kc = 0; kc < 2; ++kc) {
                int k0 = kc * 32 + lg * 8;
                vf[kc] = *(const bf16x8*)&Vt[d * 64 + (((k0 >> 3) ^ (d & 7)) << 3)];
            }
            #pragma unroll
            for (int qt = 0; qt < 2; ++qt)
                #pragma unroll
                for (int kc = 0; kc < 2; ++kc)
                    oa[dt][qt] = __builtin_amdgcn_mfma_f32_16x16x32_bf16(
                        vf[kc], pf[qt][kc], oa[dt][qt], 0, 0, 0);
        }
    }
}

// ---------------------------------------------------------------------------
// Fused local+global attention.  Block = 4 waves x 32 queries = 128 queries
// of one (partition, chunk) for one head.  Pass 1 over 512 partition keys
// (gathered), pass 2 over 256 reps.  Epilogue: per-head combined
// alpha*xl/4 + (1-alpha)*xg/4 -> plain float4 stores to xc[h] (NO atomics).
// XCD swizzle: the 4 chunks of a partition + all 4 heads share one XCD.
// ---------------------------------------------------------------------------
__global__ __launch_bounds__(256, 3) void attn_fused(
    const ushort* __restrict__ Qb, const ushort* __restrict__ Kb,
    const ushort* __restrict__ Vb,
    const ushort* __restrict__ repk, const ushort* __restrict__ repv,
    const int* __restrict__ idx, const float* __restrict__ bscore,
    const float* __restrict__ alpha_logit, const float* __restrict__ bweight,
    float* __restrict__ xc)
{
    const int work = ((blockIdx.x & 7) << 5) | (blockIdx.x >> 3);
    const int p = work >> 2, qc = work & 3;
    const int h = blockIdx.y;
    const int hofs = h * DH;
    const int tid  = threadIdx.x;
    const int wave = tid >> 6;
    const int lane = tid & 63;
    const int ln = lane & 15;
    const int lg = lane >> 4;

    __shared__ ushort Ks[64 * 64];       // 8 KB
    __shared__ ushort Vt[64 * 64];       // 8 KB
    __shared__ ushort Pb[4][32 * 64];    // 16 KB
    ushort* Pw = Pb[wave];

    const int* gidx = idx + p * SP;

    bf16x8 qf[2][2];
    int tok[2];
    #pragma unroll
    for (int qt = 0; qt < 2; ++qt) {
        int qj = wave * 32 + qt * 16 + ln;
        int t  = gidx[qc * 128 + qj];
        tok[qt] = t;
        #pragma unroll
        for (int kc = 0; kc < 2; ++kc)
            qf[qt][kc] = *(const bf16x8*)&Qb[(size_t)t * HDIM + hofs + kc * 32 + lg * 8];
    }

    f32x4 oa_l[4][2], oa_g[4][2];
    float ssl[2] = {0.f, 0.f}, ssg[2] = {0.f, 0.f};
    #pragma unroll
    for (int dt = 0; dt < 4; ++dt)
        #pragma unroll
        for (int qt = 0; qt < 2; ++qt) {
            oa_l[dt][qt] = (f32x4){0.f, 0.f, 0.f, 0.f};
            oa_g[dt][qt] = (f32x4){0.f, 0.f, 0.f, 0.f};
        }

    // pass 1: local attention over the partition's 512 keys (gathered)
    attn_pass<1>(Kb, Vb, gidx, SP, hofs, Ks, Vt, Pw,
                 qf, oa_l, ssl, tid, wave, lane, ln, lg);
    // pass 2: global attention over the 256 reps (dense rows)
    attn_pass<0>(repk, repv, gidx, NREPS, hofs, Ks, Vt, Pw,
                 qf, oa_g, ssg, tid, wave, lane, ln, lg);

    // epilogue: combine and store (plain, race-free)
    const float al = alpha_logit[0], bw = bweight[0];
    #pragma unroll
    for (int qt = 0; qt < 2; ++qt) {
        float sl = ssl[qt];
        sl += __shfl_xor(sl, 16);
        sl += __shfl_xor(sl, 32);
        float sg = ssg[qt];
        sg += __shfl_xor(sg, 16);
        sg += __shfl_xor(sg, 32);
        float a = 1.f / (1.f + __expf(-(al + bw * bscore[tok[qt]])));
        float wl = a * 0.25f / sl;
        float wg = (1.f - a) * 0.25f / sg;
        float* dst = &xc[((size_t)h * N_TOK + tok[qt]) * DH];
        #pragma unroll
        for (int dt = 0; dt < 4; ++dt) {
            float4 v;
            v.x = oa_l[dt][qt][0] * wl + oa_g[dt][qt][0] * wg;
            v.y = oa_l[dt][qt][1] * wl + oa_g[dt][qt][1] * wg;
            v.z = oa_l[dt][qt][2] * wl + oa_g[dt][qt][2] * wg;
            v.w = oa_l[dt][qt][3] * wl + oa_g[dt][qt][3] * wg;
            *(float4*)&dst[dt * 16 + lg * 4] = v;
        }
    }
}

// ---------------------------------------------------------------------------
// Kernel E: dout += sum_h xc[h].  grid 2048 x 256, float4 per thread.
// ---------------------------------------------------------------------------
__global__ __launch_bounds__(256) void combine(
    const float4* __restrict__ xc, float4* __restrict__ dout)
{
    const size_t PL = (size_t)N_TOK * DH / 4;   // plane size in float4
    const size_t i = (size_t)blockIdx.x * 256 + threadIdx.x;
    float4 a = xc[i], b = xc[i + PL], c = xc[i + 2 * PL], d = xc[i + 3 * PL];
    float4 o = dout[i];
    o.x += a.x + b.x + c.x + d.x;
    o.y += a.y + b.y + c.y + d.y;
    o.z += a.z + b.z + c.z + d.z;
    o.w += a.w + b.w + c.w + d.w;
    dout[i] = o;
}

// ---------------------------------------------------------------------------
extern "C" void kernel_launch(void* const* d_in, const int* in_sizes, int n_in,
                              void* d_out, int out_size, void* d_ws, size_t ws_size,
                              hipStream_t stream)
{
    (void)in_sizes; (void)n_in; (void)ws_size; (void)out_size;
    const float* x      = (const float*)d_in[0];
    const int*   idx    = (const int*)d_in[1];
    const float* bscore = (const float*)d_in[2];
    const float* Wq = (const float*)d_in[3]; const float* bq = (const float*)d_in[4];
    const float* Wk = (const float*)d_in[5]; const float* bk = (const float*)d_in[6];
    const float* Wv = (const float*)d_in[7]; const float* bv = (const float*)d_in[8];
    const float* seeds = (const float*)d_in[9];
    const float* al = (const float*)d_in[10];
    const float* bw = (const float*)d_in[11];
    const float* bl = (const float*)d_in[12];
    float* out = (float*)d_out;

    const size_t NE = (size_t)N_TOK * HDIM;    // 8,388,608 bf16 elems per tensor
    ushort* Qb    = (ushort*)d_ws;
    ushort* Kb    = Qb + NE;
    ushort* Vb    = Kb + NE;
    ushort* repkb = Vb + NE;
    ushort* repvb = repkb + (size_t)NREPS * HDIM;
    float*  xc    = (float*)(repvb + (size_t)NREPS * HDIM);  // 4*N*64 fp32

    qkv_mfma  <<<dim3(256, 6), 256, 0, stream>>>(x, Wq, Wk, Wv, bq, bk, bv,
                                                 Qb, Kb, Vb);
    xself_gemm<<<512, 256, 0, stream>>>(x, Wv, bv, bl, out);
    pool_reps <<<dim3(NP, NH), 512, 0, stream>>>(Kb, Vb, idx, seeds, repkb, repvb);
    attn_fused<<<dim3(256, NH), 256, 0, stream>>>(Qb, Kb, Vb, repkb, repvb,
                                                  idx, bscore, al, bw, xc);
    combine   <<<2048, 256, 0, stream>>>((const float4*)xc, (float4*)out);
}

// Round 7
// 208.765 us; speedup vs baseline: 2.0928x; 1.1606x over previous
//
#include <hip/hip_runtime.h>
#include <hip/hip_bf16.h>

#define N_TOK 32768
#define INC   256     // input channels
#define HDIM  256     // H*D
#define NH    4
#define DH    64
#define NP    64      // partitions
#define SP    512     // partition size
#define NM    4       // pool seeds
#define NREPS 256     // P*M
#define INV_SCALE 0.125f

typedef __attribute__((ext_vector_type(8))) __bf16 bf16x8;
typedef __attribute__((ext_vector_type(4))) float  f32x4;

static __device__ __forceinline__ ushort f2bf(float f) {
    __hip_bfloat16 h = __float2bfloat16(f);
    return *reinterpret_cast<ushort*>(&h);
}
static __device__ __forceinline__ float bf2f(ushort u) {
    return __uint_as_float(((uint)u) << 16);
}

#define GL_LDS16(g, l) __builtin_amdgcn_global_load_lds( \
    (const __attribute__((address_space(1))) unsigned int*)(g), \
    (__attribute__((address_space(3))) unsigned int*)(l), 16, 0, 0)

// ---------------------------------------------------------------------------
// Kernel A: QKV projection, bf16 MFMA, reading fp32 x / W directly
// (reg-staged convert + swizzled ds_write_b128).  C[128x128] per block,
// 4 waves each 32x128, BK=64.  Q pre-scaled by 1/sqrt(D)=0.125.
// grid (256 row-tiles, 6 = 3 matrices x 2 col-halves), block 256.
// ---------------------------------------------------------------------------
__global__ __launch_bounds__(256, 2) void qkv_mfma(
    const float* __restrict__ x,
    const float* __restrict__ Wq, const float* __restrict__ Wk,
    const float* __restrict__ Wv,
    const float* __restrict__ bq, const float* __restrict__ bk,
    const float* __restrict__ bv,
    ushort* __restrict__ Qb, ushort* __restrict__ Kb, ushort* __restrict__ Vb)
{
    const int bx = blockIdx.x;
    const int by = blockIdx.y;
    const int mat = by >> 1, nh = by & 1;
    const float* Wsel = (mat == 0) ? Wq : (mat == 1) ? Wk : Wv;
    const float* W = Wsel + (size_t)nh * 128 * 256;
    const float* bias = ((mat == 0) ? bq : (mat == 1) ? bk : bv) + nh * 128;
    ushort* outp = (mat == 0) ? Qb : (mat == 1) ? Kb : Vb;
    const float qscale = (mat == 0) ? INV_SCALE : 1.0f;
    const int rowBase = bx * 128;
    const int colBase = nh * 128;

    __shared__ ushort As[128 * 64];
    __shared__ ushort Bs[128 * 64];
    __shared__ ushort Cs[4][32][136];   // epilogue transpose buffer

    const int tid = threadIdx.x, wave = tid >> 6, lane = tid & 63;
    const int ln = lane & 15, lg = lane >> 4;

    f32x4 acc[2][8];
    #pragma unroll
    for (int mt = 0; mt < 2; ++mt)
        #pragma unroll
        for (int nt = 0; nt < 8; ++nt) acc[mt][nt] = (f32x4){0.f, 0.f, 0.f, 0.f};

    for (int k0 = 0; k0 < 256; k0 += 64) {
        __syncthreads();
        #pragma unroll
        for (int i = 0; i < 4; ++i) {
            int f = tid + 256 * i;          // 0..1023
            int row = f >> 3, dc = f & 7;
            int pos = (dc ^ (row & 7)) << 3;
            {
                const float* src = &x[(size_t)(rowBase + row) * 256 + k0 + dc * 8];
                float4 a = *(const float4*)&src[0];
                float4 b = *(const float4*)&src[4];
                ushort u[8] = {f2bf(a.x), f2bf(a.y), f2bf(a.z), f2bf(a.w),
                               f2bf(b.x), f2bf(b.y), f2bf(b.z), f2bf(b.w)};
                *(int4*)&As[row * 64 + pos] = *(int4*)u;
            }
            {
                const float* src = &W[(size_t)row * 256 + k0 + dc * 8];
                float4 a = *(const float4*)&src[0];
                float4 b = *(const float4*)&src[4];
                ushort u[8] = {f2bf(a.x), f2bf(a.y), f2bf(a.z), f2bf(a.w),
                               f2bf(b.x), f2bf(b.y), f2bf(b.z), f2bf(b.w)};
                *(int4*)&Bs[row * 64 + pos] = *(int4*)u;
            }
        }
        __syncthreads();

        bf16x8 af[2][2], bfr[8][2];
        #pragma unroll
        for (int mt = 0; mt < 2; ++mt)
            #pragma unroll
            for (int kk = 0; kk < 2; ++kk) {
                int row = wave * 32 + mt * 16 + ln;
                int ch  = (kk * 4 + lg) ^ (row & 7);
                af[mt][kk] = *(const bf16x8*)&As[row * 64 + ch * 8];
            }
        #pragma unroll
        for (int nt = 0; nt < 8; ++nt)
            #pragma unroll
            for (int kk = 0; kk < 2; ++kk) {
                int n  = nt * 16 + ln;
                int ch = (kk * 4 + lg) ^ (n & 7);
                bfr[nt][kk] = *(const bf16x8*)&Bs[n * 64 + ch * 8];
            }
        #pragma unroll
        for (int mt = 0; mt < 2; ++mt)
            #pragma unroll
            for (int nt = 0; nt < 8; ++nt)
                #pragma unroll
                for (int kk = 0; kk < 2; ++kk)
                    acc[mt][nt] = __builtin_amdgcn_mfma_f32_16x16x32_bf16(
                        af[mt][kk], bfr[nt][kk], acc[mt][nt], 0, 0, 0);
    }

    // epilogue: bias + (Q-only) scale + bf16, transpose via LDS, b128 stores
    float bvv[8];
    #pragma unroll
    for (int nt = 0; nt < 8; ++nt) bvv[nt] = bias[nt * 16 + ln];
    #pragma unroll
    for (int mt = 0; mt < 2; ++mt)
        #pragma unroll
        for (int nt = 0; nt < 8; ++nt)
            #pragma unroll
            for (int r = 0; r < 4; ++r)
                Cs[wave][mt * 16 + lg * 4 + r][nt * 16 + ln] =
                    f2bf((acc[mt][nt][r] + bvv[nt]) * qscale);
    __syncthreads();
    #pragma unroll
    for (int i = 0; i < 8; ++i) {
        int c = i * 64 + lane;
        int row = c >> 4, ch = c & 15;
        int4 v = *(const int4*)&Cs[wave][row][ch * 8];
        int outRow = rowBase + wave * 32 + row;
        *(int4*)&outp[(size_t)outRow * 256 + colBase + ch * 8] = v;
    }
}

// ---------------------------------------------------------------------------
// Kernel C: seed pooling -> bf16 reps.  grid (64,4), block 512.
// ---------------------------------------------------------------------------
__global__ __launch_bounds__(512) void pool_reps(
    const ushort* __restrict__ Kb, const ushort* __restrict__ Vb,
    const int* __restrict__ idx, const float* __restrict__ seeds,
    ushort* __restrict__ reps_k, ushort* __restrict__ reps_v)
{
    const int p = ((blockIdx.x & 7) << 3) | (blockIdx.x >> 3);
    const int h = blockIdx.y;
    const int tid = threadIdx.x;
    __shared__ float pexp[NM][SP];
    __shared__ float sums[NM];
    __shared__ float sred[NM][8];
    __shared__ float sd[NM][DH];
    __shared__ int   sidx[SP];

    if (tid < NM * DH) {
        int m = tid >> 6, d = tid & 63;
        sd[m][d] = seeds[(size_t)(m * NH + h) * DH + d];
    }
    sidx[tid] = idx[p * SP + tid];
    __syncthreads();

    const int n_s = sidx[tid];
    float kr[64];
    #pragma unroll
    for (int c = 0; c < 8; ++c) {
        int4 raw = *(const int4*)&Kb[(size_t)n_s * HDIM + h * DH + c * 8];
        const ushort* u = (const ushort*)&raw;
        #pragma unroll
        for (int j = 0; j < 8; ++j) kr[c * 8 + j] = bf2f(u[j]);
    }

    float e[NM];
    #pragma unroll
    for (int m = 0; m < NM; ++m) {
        float s = 0.f;
        #pragma unroll
        for (int d = 0; d < 64; ++d) s += kr[d] * sd[m][d];
        e[m] = __expf(s * INV_SCALE);
        pexp[m][tid] = e[m];
    }
    const int lane = tid & 63, w = tid >> 6;
    #pragma unroll
    for (int m = 0; m < NM; ++m) {
        float v = e[m];
        #pragma unroll
        for (int off = 32; off >= 1; off >>= 1) v += __shfl_xor(v, off);
        if (lane == 0) sred[m][w] = v;
    }
    __syncthreads();
    if (tid < NM) {
        float s = 0.f;
        #pragma unroll
        for (int i = 0; i < 8; ++i) s += sred[tid][i];
        sums[tid] = s;
    }
    __syncthreads();

    const int m = w >> 1, kv = w & 1, d = lane;
    const ushort* src = kv ? Vb : Kb;
    float acc = 0.f;
    #pragma unroll 8
    for (int s = 0; s < SP; ++s)
        acc += pexp[m][s] * bf2f(src[(size_t)sidx[s] * HDIM + h * DH + d]);
    ushort* dst = kv ? reps_v : reps_k;
    dst[(size_t)(p * NM + m) * HDIM + h * DH + d] = f2bf(acc / sums[m]);
}

// ---------------------------------------------------------------------------
// One attention pass, double-buffered (T14 async-STAGE: issue next tile's
// K global_load_lds + V global->reg loads BEFORE compute, V ds_writes AFTER;
// single barrier per tile).  GATHER=1: keys via idx; GATHER=0: dense rows.
// ---------------------------------------------------------------------------
template<int GATHER>
static __device__ __forceinline__ void attn_pass(
    const ushort* __restrict__ Kp, const ushort* __restrict__ Vp,
    const int* __restrict__ gidx, int nkeys, int hofs,
    ushort* Ks0, ushort* Ks1, ushort* Vt0, ushort* Vt1, ushort* Pw,
    const bf16x8 (&qf)[2][2], f32x4 (&oa)[4][2], float (&ssum)[2],
    int tid, int wave, int lane, int ln, int lg)
{
    const int kp = tid & 31, dc = tid >> 5;   // V staging coords

    // prologue: stage tile 0 into buffer 0
    {
        #pragma unroll
        for (int i = 0; i < 2; ++i) {
            int r0  = wave * 16 + i * 8;
            int key = r0 + (lane >> 3);
            int cc  = (lane & 7) ^ (key & 7);
            int row = GATHER ? gidx[key] : key;
            GL_LDS16(&Kp[(size_t)row * HDIM + hofs + cc * 8], &Ks0[r0 * 64]);
        }
        int r0 = GATHER ? gidx[2 * kp] : 2 * kp;
        int r1 = GATHER ? gidx[2 * kp + 1] : 2 * kp + 1;
        int4 v0 = *(const int4*)&Vp[(size_t)r0 * HDIM + hofs + dc * 8];
        int4 v1 = *(const int4*)&Vp[(size_t)r1 * HDIM + hofs + dc * 8];
        const ushort* u0 = (const ushort*)&v0;
        const ushort* u1 = (const ushort*)&v1;
        #pragma unroll
        for (int j = 0; j < 8; ++j) {
            int d = dc * 8 + j;
            uint pk = (uint)u0[j] | ((uint)u1[j] << 16);
            *(uint*)&Vt0[d * 64 + (((kp >> 2) ^ (d & 7)) << 3) + (kp & 3) * 2] = pk;
        }
    }
    __syncthreads();

    const int nt = nkeys >> 6;
    for (int t = 0; t < nt; ++t) {
        ushort* KsC = (t & 1) ? Ks1 : Ks0;
        ushort* VtC = (t & 1) ? Vt1 : Vt0;
        ushort* KsN = (t & 1) ? Ks0 : Ks1;
        ushort* VtN = (t & 1) ? Vt0 : Vt1;
        const bool pfn = (t + 1 < nt);
        int4 v0, v1;
        if (pfn) {
            int kt0 = (t + 1) << 6;
            #pragma unroll
            for (int i = 0; i < 2; ++i) {
                int r0  = wave * 16 + i * 8;
                int key = r0 + (lane >> 3);
                int cc  = (lane & 7) ^ (key & 7);
                int row = GATHER ? gidx[kt0 + key] : (kt0 + key);
                GL_LDS16(&Kp[(size_t)row * HDIM + hofs + cc * 8], &KsN[r0 * 64]);
            }
            int r0 = GATHER ? gidx[kt0 + 2 * kp] : (kt0 + 2 * kp);
            int r1 = GATHER ? gidx[kt0 + 2 * kp + 1] : (kt0 + 2 * kp + 1);
            v0 = *(const int4*)&Vp[(size_t)r0 * HDIM + hofs + dc * 8];
            v1 = *(const int4*)&Vp[(size_t)r1 * HDIM + hofs + dc * 8];
        }

        // --- scores: S^T = K x Q^T, exp, pack to P ---
        #pragma unroll
        for (int ktile = 0; ktile < 4; ++ktile) {
            int kr = ktile * 16 + ln;
            bf16x8 ka0 = *(const bf16x8*)&KsC[kr * 64 + ((lg       ^ (kr & 7)) << 3)];
            bf16x8 ka1 = *(const bf16x8*)&KsC[kr * 64 + (((4 + lg) ^ (kr & 7)) << 3)];
            #pragma unroll
            for (int qt = 0; qt < 2; ++qt) {
                f32x4 s = (f32x4){0.f, 0.f, 0.f, 0.f};
                s = __builtin_amdgcn_mfma_f32_16x16x32_bf16(ka0, qf[qt][0], s, 0, 0, 0);
                s = __builtin_amdgcn_mfma_f32_16x16x32_bf16(ka1, qf[qt][1], s, 0, 0, 0);
                float p0 = __expf(s[0]);
                float p1 = __expf(s[1]);
                float p2 = __expf(s[2]);
                float p3 = __expf(s[3]);
                ssum[qt] += (p0 + p1) + (p2 + p3);
                uint lo = (uint)f2bf(p0) | ((uint)f2bf(p1) << 16);
                uint hi = (uint)f2bf(p2) | ((uint)f2bf(p3) << 16);
                int q  = qt * 16 + ln;
                int k0 = ktile * 16 + lg * 4;
                uint2 pk; pk.x = lo; pk.y = hi;
                *(uint2*)&Pw[q * 64 + (((k0 >> 3) ^ (q & 7)) << 3) + (k0 & 7)] = pk;
            }
        }

        // --- PV: out^T += V^T x P^T ---
        bf16x8 pf[2][2];
        #pragma unroll
        for (int qt = 0; qt < 2; ++qt) {
            int q = qt * 16 + ln;
            #pragma unroll
            for (int kc = 0; kc < 2; ++kc) {
                int k0 = kc * 32 + lg * 8;
                pf[qt][kc] = *(const bf16x8*)&Pw[q * 64 + (((k0 >> 3) ^ (q & 7)) << 3)];
            }
        }
        #pragma unroll
        for (int dt = 0; dt < 4; ++dt) {
            int d = dt * 16 + ln;
            bf16x8 vf[2];
            #pragma unroll
            for (int kc = 0; kc < 2; ++kc) {
                int k0 = kc * 32 + lg * 8;
                vf[kc] = *(const bf16x8*)&VtC[d * 64 + (((k0 >> 3) ^ (d & 7)) << 3)];
            }
            #pragma unroll
            for (int qt = 0; qt < 2; ++qt)
                #pragma unroll
                for (int kc = 0; kc < 2; ++kc)
                    oa[dt][qt] = __builtin_amdgcn_mfma_f32_16x16x32_bf16(
                        vf[kc], pf[qt][kc], oa[dt][qt], 0, 0, 0);
        }

        // --- write-late: next tile's V into the other buffer ---
        if (pfn) {
            const ushort* u0 = (const ushort*)&v0;
            const ushort* u1 = (const ushort*)&v1;
            #pragma unroll
            for (int j = 0; j < 8; ++j) {
                int d = dc * 8 + j;
                uint pk = (uint)u0[j] | ((uint)u1[j] << 16);
                *(uint*)&VtN[d * 64 + (((kp >> 2) ^ (d & 7)) << 3) + (kp & 3) * 2] = pk;
            }
        }
        __syncthreads();
    }
}

// ---------------------------------------------------------------------------
// Fused local+global attention + x_self.  Block = 4 waves x 32 queries of one
// (partition, chunk) for one head.  Pass 1: 512 partition keys (gathered);
// pass 2: 256 reps.  Epilogue: alpha*xl/4 + (1-alpha)*xg/4 + beta*V_h/4
// -> plain float4 stores to xc[h] (NO atomics, no separate x_self GEMM).
// ---------------------------------------------------------------------------
__global__ __launch_bounds__(256, 3) void attn_fused(
    const ushort* __restrict__ Qb, const ushort* __restrict__ Kb,
    const ushort* __restrict__ Vb,
    const ushort* __restrict__ repk, const ushort* __restrict__ repv,
    const int* __restrict__ idx, const float* __restrict__ bscore,
    const float* __restrict__ alpha_logit, const float* __restrict__ bweight,
    const float* __restrict__ beta_logit,
    float* __restrict__ xc)
{
    const int work = ((blockIdx.x & 7) << 5) | (blockIdx.x >> 3);
    const int p = work >> 2, qc = work & 3;
    const int h = blockIdx.y;
    const int hofs = h * DH;
    const int tid  = threadIdx.x;
    const int wave = tid >> 6;
    const int lane = tid & 63;
    const int ln = lane & 15;
    const int lg = lane >> 4;

    __shared__ ushort Ks[2][64 * 64];    // 16 KB
    __shared__ ushort Vt[2][64 * 64];    // 16 KB
    __shared__ ushort Pb[4][32 * 64];    // 16 KB
    ushort* Pw = Pb[wave];

    const int* gidx = idx + p * SP;

    bf16x8 qf[2][2];
    int tok[2];
    #pragma unroll
    for (int qt = 0; qt < 2; ++qt) {
        int qj = wave * 32 + qt * 16 + ln;
        int t  = gidx[qc * 128 + qj];
        tok[qt] = t;
        #pragma unroll
        for (int kc = 0; kc < 2; ++kc)
            qf[qt][kc] = *(const bf16x8*)&Qb[(size_t)t * HDIM + hofs + kc * 32 + lg * 8];
    }

    f32x4 oa_l[4][2], oa_g[4][2];
    float ssl[2] = {0.f, 0.f}, ssg[2] = {0.f, 0.f};
    #pragma unroll
    for (int dt = 0; dt < 4; ++dt)
        #pragma unroll
        for (int qt = 0; qt < 2; ++qt) {
            oa_l[dt][qt] = (f32x4){0.f, 0.f, 0.f, 0.f};
            oa_g[dt][qt] = (f32x4){0.f, 0.f, 0.f, 0.f};
        }

    attn_pass<1>(Kb, Vb, gidx, SP, hofs, Ks[0], Ks[1], Vt[0], Vt[1], Pw,
                 qf, oa_l, ssl, tid, wave, lane, ln, lg);
    attn_pass<0>(repk, repv, gidx, NREPS, hofs, Ks[0], Ks[1], Vt[0], Vt[1], Pw,
                 qf, oa_g, ssg, tid, wave, lane, ln, lg);

    // epilogue: combine + beta*V_h/4 and store (plain, race-free)
    const float al = alpha_logit[0], bw = bweight[0];
    const float beta25 = 0.25f * 2.f / (1.f + __expf(-beta_logit[0]));
    #pragma unroll
    for (int qt = 0; qt < 2; ++qt) {
        float sl = ssl[qt];
        sl += __shfl_xor(sl, 16);
        sl += __shfl_xor(sl, 32);
        float sg = ssg[qt];
        sg += __shfl_xor(sg, 16);
        sg += __shfl_xor(sg, 32);
        float a = 1.f / (1.f + __expf(-(al + bw * bscore[tok[qt]])));
        float wl = a * 0.25f / sl;
        float wg = (1.f - a) * 0.25f / sg;
        float* dst = &xc[((size_t)h * N_TOK + tok[qt]) * DH];
        const ushort* vsrc = &Vb[(size_t)tok[qt] * HDIM + hofs];
        #pragma unroll
        for (int dt = 0; dt < 4; ++dt) {
            uint2 vv = *(const uint2*)&vsrc[dt * 16 + lg * 4];
            float4 v;
            v.x = oa_l[dt][qt][0] * wl + oa_g[dt][qt][0] * wg + beta25 * bf2f((ushort)(vv.x & 0xffff));
            v.y = oa_l[dt][qt][1] * wl + oa_g[dt][qt][1] * wg + beta25 * bf2f((ushort)(vv.x >> 16));
            v.z = oa_l[dt][qt][2] * wl + oa_g[dt][qt][2] * wg + beta25 * bf2f((ushort)(vv.y & 0xffff));
            v.w = oa_l[dt][qt][3] * wl + oa_g[dt][qt][3] * wg + beta25 * bf2f((ushort)(vv.y >> 16));
            *(float4*)&dst[dt * 16 + lg * 4] = v;
        }
    }
}

// ---------------------------------------------------------------------------
// Kernel E: dout = sum_h xc[h] (pure write).  grid 2048 x 256.
// ---------------------------------------------------------------------------
__global__ __launch_bounds__(256) void combine(
    const float4* __restrict__ xc, float4* __restrict__ dout)
{
    const size_t PL = (size_t)N_TOK * DH / 4;   // plane size in float4
    const size_t i = (size_t)blockIdx.x * 256 + threadIdx.x;
    float4 a = xc[i], b = xc[i + PL], c = xc[i + 2 * PL], d = xc[i + 3 * PL];
    float4 o;
    o.x = a.x + b.x + c.x + d.x;
    o.y = a.y + b.y + c.y + d.y;
    o.z = a.z + b.z + c.z + d.z;
    o.w = a.w + b.w + c.w + d.w;
    dout[i] = o;
}

// ---------------------------------------------------------------------------
extern "C" void kernel_launch(void* const* d_in, const int* in_sizes, int n_in,
                              void* d_out, int out_size, void* d_ws, size_t ws_size,
                              hipStream_t stream)
{
    (void)in_sizes; (void)n_in; (void)ws_size; (void)out_size;
    const float* x      = (const float*)d_in[0];
    const int*   idx    = (const int*)d_in[1];
    const float* bscore = (const float*)d_in[2];
    const float* Wq = (const float*)d_in[3]; const float* bq = (const float*)d_in[4];
    const float* Wk = (const float*)d_in[5]; const float* bk = (const float*)d_in[6];
    const float* Wv = (const float*)d_in[7]; const float* bv = (const float*)d_in[8];
    const float* seeds = (const float*)d_in[9];
    const float* al = (const float*)d_in[10];
    const float* bw = (const float*)d_in[11];
    const float* bl = (const float*)d_in[12];
    float* out = (float*)d_out;

    const size_t NE = (size_t)N_TOK * HDIM;    // 8,388,608 bf16 elems per tensor
    ushort* Qb    = (ushort*)d_ws;
    ushort* Kb    = Qb + NE;
    ushort* Vb    = Kb + NE;
    ushort* repkb = Vb + NE;
    ushort* repvb = repkb + (size_t)NREPS * HDIM;
    float*  xc    = (float*)(repvb + (size_t)NREPS * HDIM);  // 4*N*64 fp32

    qkv_mfma <<<dim3(256, 6), 256, 0, stream>>>(x, Wq, Wk, Wv, bq, bk, bv,
                                                Qb, Kb, Vb);
    pool_reps<<<dim3(NP, NH), 512, 0, stream>>>(Kb, Vb, idx, seeds, repkb, repvb);
    attn_fused<<<dim3(256, NH), 256, 0, stream>>>(Qb, Kb, Vb, repkb, repvb,
                                                  idx, bscore, al, bw, bl, xc);
    combine  <<<2048, 256, 0, stream>>>((const float4*)xc, (float4*)out);
}

// Round 10
// 196.846 us; speedup vs baseline: 2.2195x; 1.0606x over previous
//
#include <hip/hip_runtime.h>
#include <hip/hip_bf16.h>

#define N_TOK 32768
#define INC   256     // input channels
#define HDIM  256     // H*D
#define NH    4
#define DH    64
#define NP    64      // partitions
#define SP    512     // partition size
#define NM    4       // pool seeds
#define NREPS 256     // P*M
#define INV_SCALE 0.125f

typedef __attribute__((ext_vector_type(8))) __bf16 bf16x8;
typedef __attribute__((ext_vector_type(4))) float  f32x4;

static __device__ __forceinline__ ushort f2bf(float f) {
    __hip_bfloat16 h = __float2bfloat16(f);
    return *reinterpret_cast<ushort*>(&h);
}
static __device__ __forceinline__ float bf2f(ushort u) {
    return __uint_as_float(((uint)u) << 16);
}

#define GL_LDS16(g, l) __builtin_amdgcn_global_load_lds( \
    (const __attribute__((address_space(1))) unsigned int*)(g), \
    (__attribute__((address_space(3))) unsigned int*)(l), 16, 0, 0)

// ---------------------------------------------------------------------------
// Kernel 0: fp32 -> bf16 of x and the 3 weight matrices.  grid 4192 x 256.
// ---------------------------------------------------------------------------
__global__ __launch_bounds__(256) void conv_bf16(
    const float* __restrict__ x,
    const float* __restrict__ Wq, const float* __restrict__ Wk,
    const float* __restrict__ Wv,
    ushort* __restrict__ xb, ushort* __restrict__ Wb)
{
    const int b = blockIdx.x, tid = threadIdx.x;
    if (b < 4096) {                       // x: 8.4M elements, 8 per thread
        size_t base = (size_t)b * 2048 + tid * 8;
        float4 a = *(const float4*)&x[base];
        float4 c = *(const float4*)&x[base + 4];
        ushort u[8] = {f2bf(a.x), f2bf(a.y), f2bf(a.z), f2bf(a.w),
                       f2bf(c.x), f2bf(c.y), f2bf(c.z), f2bf(c.w)};
        *(int4*)&xb[base] = *(int4*)u;
    } else {                              // weights: 3 x 65536
        int wb = b - 4096;                // 0..95
        const float* W = (wb < 32) ? Wq : (wb < 64) ? Wk : Wv;
        int mat = wb >> 5;
        size_t off = (size_t)(wb & 31) * 2048 + tid * 8;
        float4 a = *(const float4*)&W[off];
        float4 c = *(const float4*)&W[off + 4];
        ushort u[8] = {f2bf(a.x), f2bf(a.y), f2bf(a.z), f2bf(a.w),
                       f2bf(c.x), f2bf(c.y), f2bf(c.z), f2bf(c.w)};
        *(int4*)&Wb[(size_t)mat * 65536 + off] = *(int4*)u;
    }
}

// ---------------------------------------------------------------------------
// Kernel A: QKV projection, bf16 MFMA, global_load_lds staging (pre-swizzled
// source, linear dest).  C[128x128] per block, 4 waves each 32x128, BK=64.
// Q pre-scaled by 1/sqrt(D)=0.125 (exact in bf16).
// grid (256 row-tiles, 6 = 3 matrices x 2 col-halves), block 256.
// ---------------------------------------------------------------------------
__global__ __launch_bounds__(256, 2) void qkv_mfma(
    const ushort* __restrict__ xb, const ushort* __restrict__ Wb,
    const float* __restrict__ bq, const float* __restrict__ bk,
    const float* __restrict__ bv,
    ushort* __restrict__ Qb, ushort* __restrict__ Kb, ushort* __restrict__ Vb)
{
    const int bx = blockIdx.x;
    const int by = blockIdx.y;
    const int mat = by >> 1, nh = by & 1;
    const ushort* W = Wb + (size_t)mat * 65536 + (size_t)nh * 128 * 256;
    const float* bias = ((mat == 0) ? bq : (mat == 1) ? bk : bv) + nh * 128;
    ushort* outp = (mat == 0) ? Qb : (mat == 1) ? Kb : Vb;
    const float qscale = (mat == 0) ? INV_SCALE : 1.0f;
    const int rowBase = bx * 128;
    const int colBase = nh * 128;

    __shared__ ushort As[128 * 64];
    __shared__ ushort Bs[128 * 64];
    __shared__ ushort Cs[4][32][136];   // epilogue transpose buffer

    const int tid = threadIdx.x, wave = tid >> 6, lane = tid & 63;
    const int ln = lane & 15, lg = lane >> 4;

    f32x4 acc[2][8];
    #pragma unroll
    for (int mt = 0; mt < 2; ++mt)
        #pragma unroll
        for (int nt = 0; nt < 8; ++nt) acc[mt][nt] = (f32x4){0.f, 0.f, 0.f, 0.f};

    for (int k0 = 0; k0 < 256; k0 += 64) {
        __syncthreads();
        #pragma unroll
        for (int i = 0; i < 4; ++i) {
            int r0 = wave * 32 + i * 8;
            int r  = r0 + (lane >> 3);
            int cc = (lane & 7) ^ (r & 7);       // inverse-swizzled source chunk
            GL_LDS16(&xb[(size_t)(rowBase + r) * 256 + k0 + cc * 8], &As[r0 * 64]);
            GL_LDS16(&W[(size_t)r * 256 + k0 + cc * 8], &Bs[r0 * 64]);
        }
        __syncthreads();

        bf16x8 af[2][2], bfr[8][2];
        #pragma unroll
        for (int mt = 0; mt < 2; ++mt)
            #pragma unroll
            for (int kk = 0; kk < 2; ++kk) {
                int row = wave * 32 + mt * 16 + ln;
                int ch  = (kk * 4 + lg) ^ (row & 7);
                af[mt][kk] = *(const bf16x8*)&As[row * 64 + ch * 8];
            }
        #pragma unroll
        for (int nt = 0; nt < 8; ++nt)
            #pragma unroll
            for (int kk = 0; kk < 2; ++kk) {
                int n  = nt * 16 + ln;
                int ch = (kk * 4 + lg) ^ (n & 7);
                bfr[nt][kk] = *(const bf16x8*)&Bs[n * 64 + ch * 8];
            }
        #pragma unroll
        for (int mt = 0; mt < 2; ++mt)
            #pragma unroll
            for (int nt = 0; nt < 8; ++nt)
                #pragma unroll
                for (int kk = 0; kk < 2; ++kk)
                    acc[mt][nt] = __builtin_amdgcn_mfma_f32_16x16x32_bf16(
                        af[mt][kk], bfr[nt][kk], acc[mt][nt], 0, 0, 0);
    }

    // epilogue: bias + (Q-only) scale + bf16, transpose via LDS, b128 stores
    float bvv[8];
    #pragma unroll
    for (int nt = 0; nt < 8; ++nt) bvv[nt] = bias[nt * 16 + ln];
    #pragma unroll
    for (int mt = 0; mt < 2; ++mt)
        #pragma unroll
        for (int nt = 0; nt < 8; ++nt)
            #pragma unroll
            for (int r = 0; r < 4; ++r)
                Cs[wave][mt * 16 + lg * 4 + r][nt * 16 + ln] =
                    f2bf((acc[mt][nt][r] + bvv[nt]) * qscale);
    __syncthreads();
    #pragma unroll
    for (int i = 0; i < 8; ++i) {
        int c = i * 64 + lane;
        int row = c >> 4, ch = c & 15;
        int4 v = *(const int4*)&Cs[wave][row][ch * 8];
        int outRow = rowBase + wave * 32 + row;
        *(int4*)&outp[(size_t)outRow * 256 + colBase + ch * 8] = v;
    }
}

// ---------------------------------------------------------------------------
// Kernel C: seed pooling -> bf16 reps.  grid (64,4), block 512.
// Segment-parallel accumulate: each wave reads a 128-token segment ONCE and
// accumulates all 4 seeds; LDS partial-sum reduce.  (4x fewer gathered loads
// than the per-(seed,wave) version.)
// ---------------------------------------------------------------------------
__global__ __launch_bounds__(512) void pool_reps(
    const ushort* __restrict__ Kb, const ushort* __restrict__ Vb,
    const int* __restrict__ idx, const float* __restrict__ seeds,
    ushort* __restrict__ reps_k, ushort* __restrict__ reps_v)
{
    const int p = ((blockIdx.x & 7) << 3) | (blockIdx.x >> 3);
    const int h = blockIdx.y;
    const int tid = threadIdx.x;
    __shared__ float pexp[NM][SP];
    __shared__ float sums[NM];
    __shared__ float sred[NM][8];
    __shared__ float sd[NM][DH];
    __shared__ int   sidx[SP];
    __shared__ float psum[2][NM][4][DH];   // [kv][seed][segment][dim]

    if (tid < NM * DH) {
        int m = tid >> 6, d = tid & 63;
        sd[m][d] = seeds[(size_t)(m * NH + h) * DH + d];
    }
    sidx[tid] = idx[p * SP + tid];
    __syncthreads();

    const int n_s = sidx[tid];
    float kr[64];
    #pragma unroll
    for (int c = 0; c < 8; ++c) {
        int4 raw = *(const int4*)&Kb[(size_t)n_s * HDIM + h * DH + c * 8];
        const ushort* u = (const ushort*)&raw;
        #pragma unroll
        for (int j = 0; j < 8; ++j) kr[c * 8 + j] = bf2f(u[j]);
    }

    float e[NM];
    #pragma unroll
    for (int m = 0; m < NM; ++m) {
        float s = 0.f;
        #pragma unroll
        for (int d = 0; d < 64; ++d) s += kr[d] * sd[m][d];
        e[m] = __expf(s * INV_SCALE);
        pexp[m][tid] = e[m];
    }
    const int lane = tid & 63, w = tid >> 6;
    #pragma unroll
    for (int m = 0; m < NM; ++m) {
        float v = e[m];
        #pragma unroll
        for (int off = 32; off >= 1; off >>= 1) v += __shfl_xor(v, off);
        if (lane == 0) sred[m][w] = v;
    }
    __syncthreads();
    if (tid < NM) {
        float s = 0.f;
        #pragma unroll
        for (int i = 0; i < 8; ++i) s += sred[tid][i];
        sums[tid] = s;
    }
    __syncthreads();

    // accumulate: wave w -> (kv = w&1, segment = w>>1), lane = dim
    {
        const int kv = w & 1, seg = w >> 1, d = lane;
        const ushort* src = kv ? Vb : Kb;
        float acc0 = 0.f, acc1 = 0.f, acc2 = 0.f, acc3 = 0.f;
        const int s0 = seg * 128;
        #pragma unroll 4
        for (int s = s0; s < s0 + 128; ++s) {
            float v = bf2f(src[(size_t)sidx[s] * HDIM + h * DH + d]);
            acc0 += pexp[0][s] * v;
            acc1 += pexp[1][s] * v;
            acc2 += pexp[2][s] * v;
            acc3 += pexp[3][s] * v;
        }
        psum[kv][0][seg][d] = acc0;
        psum[kv][1][seg][d] = acc1;
        psum[kv][2][seg][d] = acc2;
        psum[kv][3][seg][d] = acc3;
    }
    __syncthreads();

    // final reduce + store: tid -> (kv, m, d), 512 outputs exactly
    {
        const int kv = tid >> 8, m = (tid >> 6) & 3, d = tid & 63;
        float r = (psum[kv][m][0][d] + psum[kv][m][1][d]) +
                  (psum[kv][m][2][d] + psum[kv][m][3][d]);
        ushort* dst = kv ? reps_v : reps_k;
        dst[(size_t)(p * NM + m) * HDIM + h * DH + d] = f2bf(r / sums[m]);
    }
}

// ---------------------------------------------------------------------------
// One attention pass.  K double-buffered via global_load_lds; V single-buffer
// with T14 issue-early/write-late (2 barriers per tile).  setprio(1) around
// MFMA clusters (T5).  GATHER=1: keys via idx; GATHER=0: dense rows.
// ---------------------------------------------------------------------------
template<int GATHER>
static __device__ __forceinline__ void attn_pass(
    const ushort* __restrict__ Kp, const ushort* __restrict__ Vp,
    const int* __restrict__ gidx, int nkeys, int hofs,
    ushort* Ks0, ushort* Ks1, ushort* Vt, ushort* Pw,
    const bf16x8 (&qf)[2][2], f32x4 (&oa)[4][2], float (&ssum)[2],
    int tid, int wave, int lane, int ln, int lg)
{
    const int kp = tid & 31, dc = tid >> 5;   // V staging coords

    // prologue: stage tile 0
    {
        #pragma unroll
        for (int i = 0; i < 2; ++i) {
            int r0  = wave * 16 + i * 8;
            int key = r0 + (lane >> 3);
            int cc  = (lane & 7) ^ (key & 7);
            int row = GATHER ? gidx[key] : key;
            GL_LDS16(&Kp[(size_t)row * HDIM + hofs + cc * 8], &Ks0[r0 * 64]);
        }
        int r0 = GATHER ? gidx[2 * kp] : 2 * kp;
        int r1 = GATHER ? gidx[2 * kp + 1] : 2 * kp + 1;
        int4 v0 = *(const int4*)&Vp[(size_t)r0 * HDIM + hofs + dc * 8];
        int4 v1 = *(const int4*)&Vp[(size_t)r1 * HDIM + hofs + dc * 8];
        const ushort* u0 = (const ushort*)&v0;
        const ushort* u1 = (const ushort*)&v1;
        #pragma unroll
        for (int j = 0; j < 8; ++j) {
            int d = dc * 8 + j;
            uint pk = (uint)u0[j] | ((uint)u1[j] << 16);
            *(uint*)&Vt[d * 64 + (((kp >> 2) ^ (d & 7)) << 3) + (kp & 3) * 2] = pk;
        }
    }
    __syncthreads();

    const int nt = nkeys >> 6;
    for (int t = 0; t < nt; ++t) {
        ushort* KsC = (t & 1) ? Ks1 : Ks0;
        ushort* KsN = (t & 1) ? Ks0 : Ks1;
        const bool pfn = (t + 1 < nt);
        int4 v0, v1;
        if (pfn) {
            int kt0 = (t + 1) << 6;
            #pragma unroll
            for (int i = 0; i < 2; ++i) {
                int r0  = wave * 16 + i * 8;
                int key = r0 + (lane >> 3);
                int cc  = (lane & 7) ^ (key & 7);
                int row = GATHER ? gidx[kt0 + key] : (kt0 + key);
                GL_LDS16(&Kp[(size_t)row * HDIM + hofs + cc * 8], &KsN[r0 * 64]);
            }
            int r0 = GATHER ? gidx[kt0 + 2 * kp] : (kt0 + 2 * kp);
            int r1 = GATHER ? gidx[kt0 + 2 * kp + 1] : (kt0 + 2 * kp + 1);
            v0 = *(const int4*)&Vp[(size_t)r0 * HDIM + hofs + dc * 8];
            v1 = *(const int4*)&Vp[(size_t)r1 * HDIM + hofs + dc * 8];
        }

        // --- scores: S^T = K x Q^T, exp, pack to P ---
        #pragma unroll
        for (int ktile = 0; ktile < 4; ++ktile) {
            int kr = ktile * 16 + ln;
            bf16x8 ka0 = *(const bf16x8*)&KsC[kr * 64 + ((lg       ^ (kr & 7)) << 3)];
            bf16x8 ka1 = *(const bf16x8*)&KsC[kr * 64 + (((4 + lg) ^ (kr & 7)) << 3)];
            #pragma unroll
            for (int qt = 0; qt < 2; ++qt) {
                f32x4 s = (f32x4){0.f, 0.f, 0.f, 0.f};
                __builtin_amdgcn_s_setprio(1);
                s = __builtin_amdgcn_mfma_f32_16x16x32_bf16(ka0, qf[qt][0], s, 0, 0, 0);
                s = __builtin_amdgcn_mfma_f32_16x16x32_bf16(ka1, qf[qt][1], s, 0, 0, 0);
                __builtin_amdgcn_s_setprio(0);
                float p0 = __expf(s[0]);
                float p1 = __expf(s[1]);
                float p2 = __expf(s[2]);
                float p3 = __expf(s[3]);
                ssum[qt] += (p0 + p1) + (p2 + p3);
                uint lo = (uint)f2bf(p0) | ((uint)f2bf(p1) << 16);
                uint hi = (uint)f2bf(p2) | ((uint)f2bf(p3) << 16);
                int q  = qt * 16 + ln;
                int k0 = ktile * 16 + lg * 4;
                uint2 pk; pk.x = lo; pk.y = hi;
                *(uint2*)&Pw[q * 64 + (((k0 >> 3) ^ (q & 7)) << 3) + (k0 & 7)] = pk;
            }
        }

        // --- PV: out^T += V^T x P^T ---
        bf16x8 pf[2][2];
        #pragma unroll
        for (int qt = 0; qt < 2; ++qt) {
            int q = qt * 16 + ln;
            #pragma unroll
            for (int kc = 0; kc < 2; ++kc) {
                int k0 = kc * 32 + lg * 8;
                pf[qt][kc] = *(const bf16x8*)&Pw[q * 64 + (((k0 >> 3) ^ (q & 7)) << 3)];
            }
        }
        __builtin_amdgcn_s_setprio(1);
        #pragma unroll
        for (int dt = 0; dt < 4; ++dt) {
            int d = dt * 16 + ln;
            bf16x8 vf[2];
            #pragma unroll
            for (int kc = 0; kc < 2; ++kc) {
                int k0 = kc * 32 + lg * 8;
                vf[kc] = *(const bf16x8*)&Vt[d * 64 + (((k0 >> 3) ^ (d & 7)) << 3)];
            }
            #pragma unroll
            for (int qt = 0; qt < 2; ++qt)
                #pragma unroll
                for (int kc = 0; kc < 2; ++kc)
                    oa[dt][qt] = __builtin_amdgcn_mfma_f32_16x16x32_bf16(
                        vf[kc], pf[qt][kc], oa[dt][qt], 0, 0, 0);
        }
        __builtin_amdgcn_s_setprio(0);

        __syncthreads();                       // all waves done reading Vt
        if (pfn) {
            const ushort* u0 = (const ushort*)&v0;
            const ushort* u1 = (const ushort*)&v1;
            #pragma unroll
            for (int j = 0; j < 8; ++j) {
                int d = dc * 8 + j;
                uint pk = (uint)u0[j] | ((uint)u1[j] << 16);
                *(uint*)&Vt[d * 64 + (((kp >> 2) ^ (d & 7)) << 3) + (kp & 3) * 2] = pk;
            }
        }
        __syncthreads();                       // Vt ready; KsN drained
    }
}

// ---------------------------------------------------------------------------
// Fused local+global attention + x_self.  Block = 4 waves x 32 queries of one
// (partition, chunk) for one head.  LDS = 40960 B exactly -> 4 blocks/CU.
// ---------------------------------------------------------------------------
__global__ __launch_bounds__(256, 4) void attn_fused(
    const ushort* __restrict__ Qb, const ushort* __restrict__ Kb,
    const ushort* __restrict__ Vb,
    const ushort* __restrict__ repk, const ushort* __restrict__ repv,
    const int* __restrict__ idx, const float* __restrict__ bscore,
    const float* __restrict__ alpha_logit, const float* __restrict__ bweight,
    const float* __restrict__ beta_logit,
    float* __restrict__ xc)
{
    const int work = ((blockIdx.x & 7) << 5) | (blockIdx.x >> 3);
    const int p = work >> 2, qc = work & 3;
    const int h = blockIdx.y;
    const int hofs = h * DH;
    const int tid  = threadIdx.x;
    const int wave = tid >> 6;
    const int lane = tid & 63;
    const int ln = lane & 15;
    const int lg = lane >> 4;

    __shared__ ushort Ks[2][64 * 64];    // 16 KB
    __shared__ ushort Vt[64 * 64];       //  8 KB
    __shared__ ushort Pb[4][32 * 64];    // 16 KB
    ushort* Pw = Pb[wave];

    const int* gidx = idx + p * SP;

    bf16x8 qf[2][2];
    int tok[2];
    #pragma unroll
    for (int qt = 0; qt < 2; ++qt) {
        int qj = wave * 32 + qt * 16 + ln;
        int t  = gidx[qc * 128 + qj];
        tok[qt] = t;
        #pragma unroll
        for (int kc = 0; kc < 2; ++kc)
            qf[qt][kc] = *(const bf16x8*)&Qb[(size_t)t * HDIM + hofs + kc * 32 + lg * 8];
    }

    f32x4 oa_l[4][2], oa_g[4][2];
    float ssl[2] = {0.f, 0.f}, ssg[2] = {0.f, 0.f};
    #pragma unroll
    for (int dt = 0; dt < 4; ++dt)
        #pragma unroll
        for (int qt = 0; qt < 2; ++qt) {
            oa_l[dt][qt] = (f32x4){0.f, 0.f, 0.f, 0.f};
            oa_g[dt][qt] = (f32x4){0.f, 0.f, 0.f, 0.f};
        }

    attn_pass<1>(Kb, Vb, gidx, SP, hofs, Ks[0], Ks[1], Vt, Pw,
                 qf, oa_l, ssl, tid, wave, lane, ln, lg);
    attn_pass<0>(repk, repv, gidx, NREPS, hofs, Ks[0], Ks[1], Vt, Pw,
                 qf, oa_g, ssg, tid, wave, lane, ln, lg);

    // epilogue: combine + beta*V_h/4 and store (plain, race-free)
    const float al = alpha_logit[0], bw = bweight[0];
    const float beta25 = 0.25f * 2.f / (1.f + __expf(-beta_logit[0]));
    #pragma unroll
    for (int qt = 0; qt < 2; ++qt) {
        float sl = ssl[qt];
        sl += __shfl_xor(sl, 16);
        sl += __shfl_xor(sl, 32);
        float sg = ssg[qt];
        sg += __shfl_xor(sg, 16);
        sg += __shfl_xor(sg, 32);
        float a = 1.f / (1.f + __expf(-(al + bw * bscore[tok[qt]])));
        float wl = a * 0.25f / sl;
        float wg = (1.f - a) * 0.25f / sg;
        float* dst = &xc[((size_t)h * N_TOK + tok[qt]) * DH];
        const ushort* vsrc = &Vb[(size_t)tok[qt] * HDIM + hofs];
        #pragma unroll
        for (int dt = 0; dt < 4; ++dt) {
            uint2 vv = *(const uint2*)&vsrc[dt * 16 + lg * 4];
            float4 v;
            v.x = oa_l[dt][qt][0] * wl + oa_g[dt][qt][0] * wg + beta25 * bf2f((ushort)(vv.x & 0xffff));
            v.y = oa_l[dt][qt][1] * wl + oa_g[dt][qt][1] * wg + beta25 * bf2f((ushort)(vv.x >> 16));
            v.z = oa_l[dt][qt][2] * wl + oa_g[dt][qt][2] * wg + beta25 * bf2f((ushort)(vv.y & 0xffff));
            v.w = oa_l[dt][qt][3] * wl + oa_g[dt][qt][3] * wg + beta25 * bf2f((ushort)(vv.y >> 16));
            *(float4*)&dst[dt * 16 + lg * 4] = v;
        }
    }
}

// ---------------------------------------------------------------------------
// Kernel E: dout = sum_h xc[h] (pure write).  grid 2048 x 256.
// ---------------------------------------------------------------------------
__global__ __launch_bounds__(256) void combine(
    const float4* __restrict__ xc, float4* __restrict__ dout)
{
    const size_t PL = (size_t)N_TOK * DH / 4;   // plane size in float4
    const size_t i = (size_t)blockIdx.x * 256 + threadIdx.x;
    float4 a = xc[i], b = xc[i + PL], c = xc[i + 2 * PL], d = xc[i + 3 * PL];
    float4 o;
    o.x = a.x + b.x + c.x + d.x;
    o.y = a.y + b.y + c.y + d.y;
    o.z = a.z + b.z + c.z + d.z;
    o.w = a.w + b.w + c.w + d.w;
    dout[i] = o;
}

// ---------------------------------------------------------------------------
extern "C" void kernel_launch(void* const* d_in, const int* in_sizes, int n_in,
                              void* d_out, int out_size, void* d_ws, size_t ws_size,
                              hipStream_t stream)
{
    (void)in_sizes; (void)n_in; (void)ws_size; (void)out_size;
    const float* x      = (const float*)d_in[0];
    const int*   idx    = (const int*)d_in[1];
    const float* bscore = (const float*)d_in[2];
    const float* Wq = (const float*)d_in[3]; const float* bq = (const float*)d_in[4];
    const float* Wk = (const float*)d_in[5]; const float* bk = (const float*)d_in[6];
    const float* Wv = (const float*)d_in[7]; const float* bv = (const float*)d_in[8];
    const float* seeds = (const float*)d_in[9];
    const float* al = (const float*)d_in[10];
    const float* bw = (const float*)d_in[11];
    const float* bl = (const float*)d_in[12];
    float* out = (float*)d_out;

    const size_t NE = (size_t)N_TOK * HDIM;    // 8,388,608 bf16 elems per tensor
    ushort* Qb    = (ushort*)d_ws;
    ushort* Kb    = Qb + NE;
    ushort* Vb    = Kb + NE;
    ushort* repkb = Vb + NE;
    ushort* repvb = repkb + (size_t)NREPS * HDIM;
    float*  xc    = (float*)(repvb + (size_t)NREPS * HDIM);  // 4*N*64 fp32
    // xb/Wb alias the xc region: consumed by qkv_mfma BEFORE attn writes xc.
    ushort* xb    = (ushort*)xc;
    ushort* Wb    = xb + NE;

    conv_bf16<<<4192, 256, 0, stream>>>(x, Wq, Wk, Wv, xb, Wb);
    qkv_mfma <<<dim3(256, 6), 256, 0, stream>>>(xb, Wb, bq, bk, bv, Qb, Kb, Vb);
    pool_reps<<<dim3(NP, NH), 512, 0, stream>>>(Kb, Vb, idx, seeds, repkb, repvb);
    attn_fused<<<dim3(256, NH), 256, 0, stream>>>(Qb, Kb, Vb, repkb, repvb,
                                                  idx, bscore, al, bw, bl, xc);
    combine  <<<2048, 256, 0, stream>>>((const float4*)xc, (float4*)out);
}